// Round 4
// baseline (665.405 us; speedup 1.0000x reference)
//
#include <hip/hip_runtime.h>
#include <hip/hip_fp16.h>
#include <math.h>

#define N_NODES 100000
#define N_RELS  3
#define N_EDGES 400000
#define D       128
#define NTOT    (N_RELS * N_NODES)   // 300000
#define RPC     1250                 // rows per chunk (80 chunks x 1250 = 100000)
#define NCHUNK  80
#define OVW     16                   // overflow ELL width (slots 8..23)
#define OVF_CAP 4096

typedef _Float16 f16x8 __attribute__((ext_vector_type(8)));
typedef float    f32x4 __attribute__((ext_vector_type(4)));

// W transpose + fp16 convert: Wt[r][j][k] = fp16(W[r][k][j]); bsum[j] = mean_r b[r][j]
__global__ void prep_w_kernel(const float* __restrict__ W, const float* __restrict__ b,
                              ushort* __restrict__ Wt, float* __restrict__ bsum) {
    int id = blockIdx.x * 256 + threadIdx.x;
    if (id < 3 * D * D) {
        int r = id >> 14;
        int rem = id & 16383;
        int k = rem >> 7, j = rem & 127;
        Wt[r * 16384 + j * 128 + k] = __builtin_bit_cast(ushort, (_Float16)W[id]);
    }
    if (blockIdx.x == 0 && threadIdx.x < D) {
        int j = threadIdx.x;
        bsum[j] = (b[j] + b[D + j] + b[2 * D + j]) * (1.0f / 3.0f);
    }
}

// One kernel, zero global atomics (except rare ovf list): each block owns a
// 1250-node range of one relation, scans that relation's whole edge list,
// histograms in-degree/out-degree and fills an 8-wide ELL in LDS.
__global__ __launch_bounds__(256) void build_kernel(
    const int* __restrict__ edges, int* __restrict__ deg_in_g,
    float* __restrict__ rdi, float* __restrict__ rdo,
    int* __restrict__ ell8, int* __restrict__ ell_ovf,
    int* __restrict__ ovf_cnt, int2* __restrict__ ovf) {
    __shared__ int cnt[RPC];
    __shared__ int dout[RPC];
    __shared__ int slots[RPC * 8];
    const int rel  = blockIdx.y;
    const int row0 = blockIdx.x * RPC;
    for (int i = threadIdx.x; i < RPC; i += 256) { cnt[i] = 0; dout[i] = 0; }
    __syncthreads();
    const int* src = edges + (size_t)(rel * 2 + 0) * N_EDGES;
    const int* dst = edges + (size_t)(rel * 2 + 1) * N_EDGES;
    for (int e = threadIdx.x; e < N_EDGES; e += 256) {
        int s = src[e], t = dst[e];
        unsigned ds = (unsigned)(s - row0);
        if (ds < RPC) atomicAdd(&dout[ds], 1);
        unsigned dt = (unsigned)(t - row0);
        if (dt < RPC) {
            int p = atomicAdd(&cnt[dt], 1);
            if (p < 8) {
                slots[dt * 8 + p] = s;
            } else if (p < 8 + OVW) {
                ell_ovf[(size_t)(rel * N_NODES + t) * OVW + (p - 8)] = s;
            } else {
                int i = atomicAdd(ovf_cnt, 1);
                if (i < OVF_CAP) ovf[i] = make_int2(s, t | (rel << 20));
            }
        }
    }
    __syncthreads();
    const int base = rel * N_NODES + row0;
    for (int i = threadIdx.x; i < RPC; i += 256) {
        int c = cnt[i];
        deg_in_g[base + i] = c;
        rdi[base + i] = rsqrtf((float)max(c, 1));
        rdo[base + i] = rsqrtf((float)max(dout[i], 1));
    }
    int4*       dp = (int4*)(ell8 + (size_t)base * 8);
    const int4* sp = (const int4*)slots;
    for (int i = threadIdx.x; i < RPC * 2; i += 256) dp[i] = sp[i];
}

// h[n, rel*128+j] = fp16( rdo[rel][n] * sum_k x[n,k] W[rel][k][j] )
// Flat grid over 128-row tiles. A fragments (fp16, 32 VGPR) loaded once,
// reused across the rel loop; per rel stage Wt (32 KB LDS, XOR swizzle).
// 4 waves, each owns 32 rows x 128 cols.
__global__ __launch_bounds__(256) void gemm_h_kernel(
    const float* __restrict__ x, const ushort* __restrict__ Wt,
    const float* __restrict__ rdo, ushort* __restrict__ h) {
    __shared__ ushort Bt[128 * 128];   // 32 KB
    const int n0  = blockIdx.x * 128;
    const int tid = threadIdx.x;
    const int w = tid >> 6, l = tid & 63;
    const int wrow = w * 32;
    const int lr = l & 15, lk = (l >> 4) * 8;

    // A fragments: a[fi][ks], rows n0+wrow+fi*16+lr, k = ks*32+lk..+7
    f16x8 a[2][4];
    #pragma unroll
    for (int fi = 0; fi < 2; ++fi) {
        int row = n0 + wrow + fi * 16 + lr;
        row = min(row, N_NODES - 1);
        const float* xp = x + (size_t)row * 128 + lk;
        #pragma unroll
        for (int ks = 0; ks < 4; ++ks) {
            float4 va = *(const float4*)(xp + ks * 32);
            float4 vb = *(const float4*)(xp + ks * 32 + 4);
            f16x8 t;
            t[0] = (_Float16)va.x; t[1] = (_Float16)va.y;
            t[2] = (_Float16)va.z; t[3] = (_Float16)va.w;
            t[4] = (_Float16)vb.x; t[5] = (_Float16)vb.y;
            t[6] = (_Float16)vb.z; t[7] = (_Float16)vb.w;
            a[fi][ks] = t;
        }
    }

    for (int rel = 0; rel < 3; ++rel) {
        __syncthreads();   // protect Bt readers from previous rel
        {
            const ushort* Wg = Wt + rel * 16384;
            #pragma unroll
            for (int c = 0; c < 8; ++c) {
                int id = c * 256 + tid;
                int j = id >> 4, k8 = id & 15;
                uint4 v = *(const uint4*)(Wg + j * 128 + k8 * 8);
                int ba = (j * 256 + k8 * 16) ^ ((j & 7) << 4);
                *(uint4*)((char*)Bt + ba) = v;
            }
        }
        __syncthreads();

        f32x4 acc[2][8];
        #pragma unroll
        for (int fi = 0; fi < 2; ++fi)
            #pragma unroll
            for (int fj = 0; fj < 8; ++fj)
                acc[fi][fj] = (f32x4){0.f, 0.f, 0.f, 0.f};

        #pragma unroll
        for (int ks = 0; ks < 4; ++ks) {
            f16x8 bfr[8];
            #pragma unroll
            for (int fj = 0; fj < 8; ++fj) {
                int j = fj * 16 + lr;
                int ba = (j * 256 + (ks * 32 + lk) * 2) ^ ((j & 7) << 4);
                bfr[fj] = *(f16x8*)((char*)Bt + ba);
            }
            #pragma unroll
            for (int fi = 0; fi < 2; ++fi)
                #pragma unroll
                for (int fj = 0; fj < 8; ++fj)
                    acc[fi][fj] = __builtin_amdgcn_mfma_f32_16x16x32_f16(
                        a[fi][ks], bfr[fj], acc[fi][fj], 0, 0, 0);
        }

        // epilogue: C/D col = lane&15, row = (lane>>4)*4 + i
        const int cr4 = (l >> 4) * 4;
        #pragma unroll
        for (int fi = 0; fi < 2; ++fi) {
            int rbase = n0 + wrow + fi * 16 + cr4;
            float sc[4];
            #pragma unroll
            for (int i = 0; i < 4; ++i) {
                int row = rbase + i;
                sc[i] = (row < N_NODES) ? rdo[rel * N_NODES + row] : 0.f;
            }
            #pragma unroll
            for (int fj = 0; fj < 8; ++fj) {
                int col = fj * 16 + lr;
                #pragma unroll
                for (int i = 0; i < 4; ++i) {
                    int row = rbase + i;
                    if (row < N_NODES)
                        h[(size_t)row * 384 + rel * 128 + col] =
                            __builtin_bit_cast(ushort, (_Float16)(acc[fi][fj][i] * sc[i]));
                }
            }
        }
    }
}

// out[n,:] = (1/3) sum_r rdi_r[n] * sum_{e} h[src_e, r*128:(r+1)*128] + bsum
// One wave per node; lane covers cols 2l, 2l+1 (one u32 = 2 fp16).
__global__ __launch_bounds__(256) void gather_kernel(
    const ushort* __restrict__ h, const int* __restrict__ deg_in_g,
    const int* __restrict__ ell8, const int* __restrict__ ell_ovf,
    const float* __restrict__ rdi, const float* __restrict__ bsum,
    float* __restrict__ out) {
    int w = threadIdx.x >> 6, l = threadIdx.x & 63;
    int n = blockIdx.x * 4 + w;
    if (n >= N_NODES) return;
    float ox = 0.f, oy = 0.f;
    #pragma unroll
    for (int r = 0; r < 3; ++r) {
        int base = r * N_NODES + n;
        int cnt = min(deg_in_g[base], 8 + OVW);
        int e = 0;
        if (l < cnt)
            e = (l < 8) ? ell8[(size_t)base * 8 + l]
                        : ell_ovf[(size_t)base * OVW + (l - 8)];
        float ax = 0.f, ay = 0.f;
        int i = 0;
        for (; i + 2 <= cnt; i += 2) {
            int s0 = __shfl(e, i), s1 = __shfl(e, i + 1);
            uint u0 = *(const uint*)(h + (size_t)s0 * 384 + r * 128 + 2 * l);
            uint u1 = *(const uint*)(h + (size_t)s1 * 384 + r * 128 + 2 * l);
            __half2 h0 = __builtin_bit_cast(__half2, u0);
            __half2 h1 = __builtin_bit_cast(__half2, u1);
            ax += __low2float(h0) + __low2float(h1);
            ay += __high2float(h0) + __high2float(h1);
        }
        if (i < cnt) {
            int s0 = __shfl(e, i);
            uint u0 = *(const uint*)(h + (size_t)s0 * 384 + r * 128 + 2 * l);
            __half2 h0 = __builtin_bit_cast(__half2, u0);
            ax += __low2float(h0);
            ay += __high2float(h0);
        }
        float sc = rdi[base];
        ox = fmaf(ax, sc, ox);
        oy = fmaf(ay, sc, oy);
    }
    float2 bs = *(const float2*)(bsum + 2 * l);
    float2 o;
    o.x = ox * (1.f / 3.f) + bs.x;
    o.y = oy * (1.f / 3.f) + bs.y;
    *(float2*)(out + (size_t)n * 128 + 2 * l) = o;
}

// Rare path: in-degree > 24. Atomic add into out (runs after gather).
__global__ void ovf_kernel(const ushort* __restrict__ h, const float* __restrict__ rdi,
                           const int* __restrict__ ovf_cnt, const int2* __restrict__ ovf,
                           float* out) {
    int m = min(*ovf_cnt, OVF_CAP);
    int total = m * 64;
    for (int idx = blockIdx.x * blockDim.x + threadIdx.x; idx < total;
         idx += blockDim.x * gridDim.x) {
        int ent = idx >> 6, l = idx & 63;
        int s = ovf[ent].x;
        int packed = ovf[ent].y;
        int t = packed & 0xFFFFF, r = packed >> 20;
        uint u = *(const uint*)(h + (size_t)s * 384 + r * 128 + 2 * l);
        __half2 hv = __builtin_bit_cast(__half2, u);
        float sc = rdi[r * N_NODES + t] * (1.f / 3.f);
        atomicAdd(out + (size_t)t * 128 + 2 * l + 0, __low2float(hv) * sc);
        atomicAdd(out + (size_t)t * 128 + 2 * l + 1, __high2float(hv) * sc);
    }
}

extern "C" void kernel_launch(void* const* d_in, const int* in_sizes, int n_in,
                              void* d_out, int out_size, void* d_ws, size_t ws_size,
                              hipStream_t stream) {
    const float* x     = (const float*)d_in[0];
    const int*   edges = (const int*)d_in[1];   // [R][2][E] int32
    const float* W     = (const float*)d_in[2]; // [R][D][D]
    const float* b     = (const float*)d_in[3]; // [R][D]
    float* out = (float*)d_out;

    char* ws = (char*)d_ws;
    size_t off = 0;
    auto alloc = [&](size_t bytes) -> void* {
        void* p = ws + off;
        off += (bytes + 255) & ~(size_t)255;
        return p;
    };
    int*   ovf_cnt  = (int*)alloc(256);                       // memset'd
    int*   deg_in_g = (int*)alloc((size_t)NTOT * 4);
    float* rdi      = (float*)alloc((size_t)NTOT * 4);
    float* rdo      = (float*)alloc((size_t)NTOT * 4);
    float* bsum     = (float*)alloc((size_t)D * 4);
    ushort* Wt      = (ushort*)alloc((size_t)3 * D * D * 2);
    int2*  ovf      = (int2*)alloc((size_t)OVF_CAP * 8);
    int*   ell8     = (int*)alloc((size_t)NTOT * 8 * 4);      // 9.6 MB
    int*   ell_ovf  = (int*)alloc((size_t)NTOT * OVW * 4);    // 19.2 MB
    ushort* h       = (ushort*)alloc((size_t)N_NODES * 3 * D * 2); // 76.8 MB

    hipMemsetAsync(ovf_cnt, 0, 256, stream);
    prep_w_kernel<<<192, 256, 0, stream>>>(W, b, Wt, bsum);
    build_kernel<<<dim3(NCHUNK, 3), 256, 0, stream>>>(
        edges, deg_in_g, rdi, rdo, ell8, ell_ovf, ovf_cnt, ovf);
    gemm_h_kernel<<<(N_NODES + 127) / 128, 256, 0, stream>>>(x, Wt, rdo, h);
    gather_kernel<<<(N_NODES + 3) / 4, 256, 0, stream>>>(
        h, deg_in_g, ell8, ell_ovf, rdi, bsum, out);
    ovf_kernel<<<16, 256, 0, stream>>>(h, rdi, ovf_cnt, ovf, out);
}

// Round 5
// 241.909 us; speedup vs baseline: 2.7506x; 2.7506x over previous
//
#include <hip/hip_runtime.h>
#include <hip/hip_fp16.h>
#include <math.h>

#define N_NODES 100000
#define N_RELS  3
#define N_EDGES 400000
#define D       128
#define NTOT    (N_RELS * N_NODES)   // 300000
#define ELL_W   12
#define OVF_CAP 4096

typedef _Float16 f16x8 __attribute__((ext_vector_type(8)));
typedef float    f32x4 __attribute__((ext_vector_type(4)));

// W transpose + fp16 convert: Wt[r][j][k] = fp16(W[r][k][j]); bsum[j] = mean_r b[r][j]
__global__ void prep_w_kernel(const float* __restrict__ W, const float* __restrict__ b,
                              ushort* __restrict__ Wt, float* __restrict__ bsum) {
    int id = blockIdx.x * 256 + threadIdx.x;
    if (id < 3 * D * D) {
        int r = id >> 14;
        int rem = id & 16383;
        int k = rem >> 7, j = rem & 127;
        Wt[r * 16384 + j * 128 + k] = __builtin_bit_cast(ushort, (_Float16)W[id]);
    }
    if (blockIdx.x == 0 && threadIdx.x < D) {
        int j = threadIdx.x;
        bsum[j] = (b[j] + b[D + j] + b[2 * D + j]) * (1.0f / 3.0f);
    }
}

// Single preprocessing pass: out-degree histogram + ELL12 fill. 4 edges/thread.
__global__ __launch_bounds__(256) void fill_kernel(
    const int* __restrict__ edges, int* __restrict__ deg_out,
    int* __restrict__ cursor, int* __restrict__ ell,
    int* __restrict__ ovf_cnt, int2* __restrict__ ovf) {
    int e0 = (blockIdx.x * 256 + threadIdx.x) * 4;
    int rel = blockIdx.y;
    if (e0 >= N_EDGES) return;
    const int* src = edges + (size_t)(rel * 2 + 0) * N_EDGES;
    const int* dst = edges + (size_t)(rel * 2 + 1) * N_EDGES;
    int4 s4 = *(const int4*)(src + e0);
    int4 t4 = *(const int4*)(dst + e0);
    int ss[4] = {s4.x, s4.y, s4.z, s4.w};
    int tt[4] = {t4.x, t4.y, t4.z, t4.w};
    #pragma unroll
    for (int k = 0; k < 4; ++k) {
        atomicAdd(deg_out + rel * N_NODES + ss[k], 1);
        int p = atomicAdd(cursor + rel * N_NODES + tt[k], 1);
        if (p < ELL_W) {
            ell[(size_t)(rel * N_NODES + tt[k]) * ELL_W + p] = ss[k];
        } else {
            int i = atomicAdd(ovf_cnt, 1);
            if (i < OVF_CAP) ovf[i] = make_int2(ss[k], tt[k] | (rel << 20));
        }
    }
}

// h[n, rel*128+j] = fp16( rsqrt(deg_out[rel][n]) * sum_k x[n,k] W[rel][k][j] )
// Flat grid over 128-row tiles. A fragments (fp16, 32 VGPR) loaded once,
// reused across the rel loop; per rel stage Wt (32 KB LDS, XOR swizzle).
__global__ __launch_bounds__(256) void gemm_h_kernel(
    const float* __restrict__ x, const ushort* __restrict__ Wt,
    const int* __restrict__ deg_out, ushort* __restrict__ h) {
    __shared__ ushort Bt[128 * 128];   // 32 KB
    const int n0  = blockIdx.x * 128;
    const int tid = threadIdx.x;
    const int w = tid >> 6, l = tid & 63;
    const int wrow = w * 32;
    const int lr = l & 15, lk = (l >> 4) * 8;

    // A fragments: a[fi][ks], rows n0+wrow+fi*16+lr, k = ks*32+lk..+7
    f16x8 a[2][4];
    #pragma unroll
    for (int fi = 0; fi < 2; ++fi) {
        int row = n0 + wrow + fi * 16 + lr;
        row = min(row, N_NODES - 1);
        const float* xp = x + (size_t)row * 128 + lk;
        #pragma unroll
        for (int ks = 0; ks < 4; ++ks) {
            float4 va = *(const float4*)(xp + ks * 32);
            float4 vb = *(const float4*)(xp + ks * 32 + 4);
            f16x8 t;
            t[0] = (_Float16)va.x; t[1] = (_Float16)va.y;
            t[2] = (_Float16)va.z; t[3] = (_Float16)va.w;
            t[4] = (_Float16)vb.x; t[5] = (_Float16)vb.y;
            t[6] = (_Float16)vb.z; t[7] = (_Float16)vb.w;
            a[fi][ks] = t;
        }
    }

    for (int rel = 0; rel < 3; ++rel) {
        __syncthreads();   // protect Bt readers from previous rel
        {
            const ushort* Wg = Wt + rel * 16384;
            #pragma unroll
            for (int c = 0; c < 8; ++c) {
                int id = c * 256 + tid;
                int j = id >> 4, k8 = id & 15;
                uint4 v = *(const uint4*)(Wg + j * 128 + k8 * 8);
                int ba = (j * 256 + k8 * 16) ^ ((j & 7) << 4);
                *(uint4*)((char*)Bt + ba) = v;
            }
        }
        __syncthreads();

        f32x4 acc[2][8];
        #pragma unroll
        for (int fi = 0; fi < 2; ++fi)
            #pragma unroll
            for (int fj = 0; fj < 8; ++fj)
                acc[fi][fj] = (f32x4){0.f, 0.f, 0.f, 0.f};

        #pragma unroll
        for (int ks = 0; ks < 4; ++ks) {
            f16x8 bfr[8];
            #pragma unroll
            for (int fj = 0; fj < 8; ++fj) {
                int j = fj * 16 + lr;
                int ba = (j * 256 + (ks * 32 + lk) * 2) ^ ((j & 7) << 4);
                bfr[fj] = *(f16x8*)((char*)Bt + ba);
            }
            #pragma unroll
            for (int fi = 0; fi < 2; ++fi)
                #pragma unroll
                for (int fj = 0; fj < 8; ++fj)
                    acc[fi][fj] = __builtin_amdgcn_mfma_f32_16x16x32_f16(
                        a[fi][ks], bfr[fj], acc[fi][fj], 0, 0, 0);
        }

        // epilogue: C/D col = lane&15, row = (lane>>4)*4 + i
        const int cr4 = (l >> 4) * 4;
        #pragma unroll
        for (int fi = 0; fi < 2; ++fi) {
            int rbase = n0 + wrow + fi * 16 + cr4;
            float sc[4];
            #pragma unroll
            for (int i = 0; i < 4; ++i) {
                int row = rbase + i;
                sc[i] = (row < N_NODES)
                    ? rsqrtf((float)max(deg_out[rel * N_NODES + row], 1)) : 0.f;
            }
            #pragma unroll
            for (int fj = 0; fj < 8; ++fj) {
                int col = fj * 16 + lr;
                #pragma unroll
                for (int i = 0; i < 4; ++i) {
                    int row = rbase + i;
                    if (row < N_NODES)
                        h[(size_t)row * 384 + rel * 128 + col] =
                            __builtin_bit_cast(ushort, (_Float16)(acc[fi][fj][i] * sc[i]));
                }
            }
        }
    }
}

// out[n,:] = (1/3) sum_r rsqrt(deg_in_r[n]) * sum_e h[src_e, r*128:(r+1)*128] + bsum
// One wave per node; lane covers cols 2l, 2l+1 (one u32 = 2 fp16).
__global__ __launch_bounds__(256) void gather_kernel(
    const ushort* __restrict__ h, const int* __restrict__ cursor,
    const int* __restrict__ ell, const float* __restrict__ bsum,
    float* __restrict__ out) {
    int w = threadIdx.x >> 6, l = threadIdx.x & 63;
    int n = blockIdx.x * 4 + w;
    if (n >= N_NODES) return;
    float ox = 0.f, oy = 0.f;
    #pragma unroll
    for (int r = 0; r < 3; ++r) {
        int base = r * N_NODES + n;
        int deg = cursor[base];
        int cnt = min(deg, ELL_W);
        int e = 0;
        if (l < cnt) e = ell[(size_t)base * ELL_W + l];
        float ax = 0.f, ay = 0.f;
        int i = 0;
        for (; i + 2 <= cnt; i += 2) {
            int s0 = __shfl(e, i), s1 = __shfl(e, i + 1);
            uint u0 = *(const uint*)(h + (size_t)s0 * 384 + r * 128 + 2 * l);
            uint u1 = *(const uint*)(h + (size_t)s1 * 384 + r * 128 + 2 * l);
            __half2 h0 = __builtin_bit_cast(__half2, u0);
            __half2 h1 = __builtin_bit_cast(__half2, u1);
            ax += __low2float(h0) + __low2float(h1);
            ay += __high2float(h0) + __high2float(h1);
        }
        if (i < cnt) {
            int s0 = __shfl(e, i);
            uint u0 = *(const uint*)(h + (size_t)s0 * 384 + r * 128 + 2 * l);
            __half2 h0 = __builtin_bit_cast(__half2, u0);
            ax += __low2float(h0);
            ay += __high2float(h0);
        }
        float sc = rsqrtf((float)max(deg, 1));
        ox = fmaf(ax, sc, ox);
        oy = fmaf(ay, sc, oy);
    }
    float2 bs = *(const float2*)(bsum + 2 * l);
    float2 o;
    o.x = ox * (1.f / 3.f) + bs.x;
    o.y = oy * (1.f / 3.f) + bs.y;
    *(float2*)(out + (size_t)n * 128 + 2 * l) = o;
}

// Rare path: in-degree > ELL_W (expect ~100 edges). Atomic add into out.
__global__ void ovf_kernel(const ushort* __restrict__ h, const int* __restrict__ cursor,
                           const int* __restrict__ ovf_cnt, const int2* __restrict__ ovf,
                           float* out) {
    int m = min(*ovf_cnt, OVF_CAP);
    int total = m * 64;
    for (int idx = blockIdx.x * blockDim.x + threadIdx.x; idx < total;
         idx += blockDim.x * gridDim.x) {
        int ent = idx >> 6, l = idx & 63;
        int s = ovf[ent].x;
        int packed = ovf[ent].y;
        int t = packed & 0xFFFFF, r = packed >> 20;
        uint u = *(const uint*)(h + (size_t)s * 384 + r * 128 + 2 * l);
        __half2 hv = __builtin_bit_cast(__half2, u);
        float sc = rsqrtf((float)max(cursor[r * N_NODES + t], 1)) * (1.f / 3.f);
        atomicAdd(out + (size_t)t * 128 + 2 * l + 0, __low2float(hv) * sc);
        atomicAdd(out + (size_t)t * 128 + 2 * l + 1, __high2float(hv) * sc);
    }
}

extern "C" void kernel_launch(void* const* d_in, const int* in_sizes, int n_in,
                              void* d_out, int out_size, void* d_ws, size_t ws_size,
                              hipStream_t stream) {
    const float* x     = (const float*)d_in[0];
    const int*   edges = (const int*)d_in[1];   // [R][2][E] int32
    const float* W     = (const float*)d_in[2]; // [R][D][D]
    const float* b     = (const float*)d_in[3]; // [R][D]
    float* out = (float*)d_out;

    char* ws = (char*)d_ws;
    size_t off = 0;
    auto alloc = [&](size_t bytes) -> void* {
        void* p = ws + off;
        off += (bytes + 255) & ~(size_t)255;
        return p;
    };
    int*   deg_out = (int*)alloc((size_t)NTOT * 4);
    int*   cursor  = (int*)alloc((size_t)NTOT * 4);
    int*   ovf_cnt = (int*)alloc(256);
    size_t zero_bytes = off;                       // memset deg_out+cursor+ovf_cnt
    float* bsum    = (float*)alloc((size_t)D * 4);
    ushort* Wt     = (ushort*)alloc((size_t)3 * D * D * 2);
    int2*  ovf     = (int2*)alloc((size_t)OVF_CAP * 8);
    int*   ell     = (int*)alloc((size_t)NTOT * ELL_W * 4);        // 14.4 MB
    ushort* h      = (ushort*)alloc((size_t)N_NODES * 3 * D * 2);  // 76.8 MB

    hipMemsetAsync(ws, 0, zero_bytes, stream);
    prep_w_kernel<<<192, 256, 0, stream>>>(W, b, Wt, bsum);
    fill_kernel<<<dim3((N_EDGES / 4 + 255) / 256, 3), 256, 0, stream>>>(
        edges, deg_out, cursor, ell, ovf_cnt, ovf);
    gemm_h_kernel<<<(N_NODES + 127) / 128, 256, 0, stream>>>(x, Wt, deg_out, h);
    gather_kernel<<<(N_NODES + 3) / 4, 256, 0, stream>>>(h, cursor, ell, bsum, out);
    ovf_kernel<<<16, 256, 0, stream>>>(h, cursor, ovf_cnt, ovf, out);
}

// Round 6
// 210.559 us; speedup vs baseline: 3.1602x; 1.1489x over previous
//
#include <hip/hip_runtime.h>
#include <hip/hip_fp16.h>
#include <math.h>

#define N_NODES 100000
#define N_RELS  3
#define N_EDGES 400000
#define D       128
#define NTOT    (N_RELS * N_NODES)   // 300000
#define ELL_W   12
#define OVF_CAP 4096
#define CPAD    3                    // counter stride = 1<<CPAD ints = 32 B
#define GEMM_BLKS 782                // ceil(100000/128)
#define FILL_CHUNKS 391              // ceil(400000/1024) per relation
#define FILL_BLKS (FILL_CHUNKS * 3)  // 1173

typedef _Float16 f16x8 __attribute__((ext_vector_type(8)));
typedef float    f32x4 __attribute__((ext_vector_type(4)));

// W transpose + fp16 convert: Wt[r][j][k] = fp16(W[r][k][j]); bsum[j] = mean_r b[r][j]
__global__ void prep_w_kernel(const float* __restrict__ W, const float* __restrict__ b,
                              ushort* __restrict__ Wt, float* __restrict__ bsum) {
    int id = blockIdx.x * 256 + threadIdx.x;
    if (id < 3 * D * D) {
        int r = id >> 14;
        int rem = id & 16383;
        int k = rem >> 7, j = rem & 127;
        Wt[r * 16384 + j * 128 + k] = __builtin_bit_cast(ushort, (_Float16)W[id]);
    }
    if (blockIdx.x == 0 && threadIdx.x < D) {
        int j = threadIdx.x;
        bsum[j] = (b[j] + b[D + j] + b[2 * D + j]) * (1.0f / 3.0f);
    }
}

// Fused kernel: even blocks < 1564 compute h = fp16(x @ W_rel) (MFMA);
// remaining blocks do the edge pass (padded atomics + ELL12 fill).
// The two halves are data-independent; co-residency hides atomic latency
// under MFMA work.
__global__ __launch_bounds__(256) void fused_kernel(
    const float* __restrict__ x, const ushort* __restrict__ Wt,
    const int* __restrict__ edges, ushort* __restrict__ h,
    int* __restrict__ deg_pad, int* __restrict__ cur_pad,
    int* __restrict__ ell, int* __restrict__ ovf_cnt, int2* __restrict__ ovf) {
    const int bid = blockIdx.x;
    const int tid = threadIdx.x;
    const bool is_gemm = (bid < 2 * GEMM_BLKS) && ((bid & 1) == 0);

    if (is_gemm) {
        __shared__ ushort Bt[128 * 128];   // 32 KB
        const int n0 = (bid >> 1) * 128;
        const int w = tid >> 6, l = tid & 63;
        const int wrow = w * 32;
        const int lr = l & 15, lk = (l >> 4) * 8;

        // A fragments: a[fi][ks], rows n0+wrow+fi*16+lr, k = ks*32+lk..+7
        f16x8 a[2][4];
        #pragma unroll
        for (int fi = 0; fi < 2; ++fi) {
            int row = n0 + wrow + fi * 16 + lr;
            row = min(row, N_NODES - 1);
            const float* xp = x + (size_t)row * 128 + lk;
            #pragma unroll
            for (int ks = 0; ks < 4; ++ks) {
                float4 va = *(const float4*)(xp + ks * 32);
                float4 vb = *(const float4*)(xp + ks * 32 + 4);
                f16x8 t;
                t[0] = (_Float16)va.x; t[1] = (_Float16)va.y;
                t[2] = (_Float16)va.z; t[3] = (_Float16)va.w;
                t[4] = (_Float16)vb.x; t[5] = (_Float16)vb.y;
                t[6] = (_Float16)vb.z; t[7] = (_Float16)vb.w;
                a[fi][ks] = t;
            }
        }

        for (int rel = 0; rel < 3; ++rel) {
            __syncthreads();
            {
                const ushort* Wg = Wt + rel * 16384;
                #pragma unroll
                for (int c = 0; c < 8; ++c) {
                    int id = c * 256 + tid;
                    int j = id >> 4, k8 = id & 15;
                    uint4 v = *(const uint4*)(Wg + j * 128 + k8 * 8);
                    int ba = (j * 256 + k8 * 16) ^ ((j & 7) << 4);
                    *(uint4*)((char*)Bt + ba) = v;
                }
            }
            __syncthreads();

            f32x4 acc[2][8];
            #pragma unroll
            for (int fi = 0; fi < 2; ++fi)
                #pragma unroll
                for (int fj = 0; fj < 8; ++fj)
                    acc[fi][fj] = (f32x4){0.f, 0.f, 0.f, 0.f};

            #pragma unroll
            for (int ks = 0; ks < 4; ++ks) {
                f16x8 bfr[8];
                #pragma unroll
                for (int fj = 0; fj < 8; ++fj) {
                    int j = fj * 16 + lr;
                    int ba = (j * 256 + (ks * 32 + lk) * 2) ^ ((j & 7) << 4);
                    bfr[fj] = *(f16x8*)((char*)Bt + ba);
                }
                #pragma unroll
                for (int fi = 0; fi < 2; ++fi)
                    #pragma unroll
                    for (int fj = 0; fj < 8; ++fj)
                        acc[fi][fj] = __builtin_amdgcn_mfma_f32_16x16x32_f16(
                            a[fi][ks], bfr[fj], acc[fi][fj], 0, 0, 0);
            }

            // epilogue: C/D col = lane&15, row = (lane>>4)*4 + i (no scaling)
            const int cr4 = (l >> 4) * 4;
            #pragma unroll
            for (int fi = 0; fi < 2; ++fi) {
                int rbase = n0 + wrow + fi * 16 + cr4;
                #pragma unroll
                for (int fj = 0; fj < 8; ++fj) {
                    int col = fj * 16 + lr;
                    #pragma unroll
                    for (int i = 0; i < 4; ++i) {
                        int row = rbase + i;
                        if (row < N_NODES)
                            h[(size_t)row * 384 + rel * 128 + col] =
                                __builtin_bit_cast(ushort, (_Float16)acc[fi][fj][i]);
                    }
                }
            }
        }
    } else {
        int fid = (bid < 2 * GEMM_BLKS) ? (bid >> 1) : (bid - GEMM_BLKS);
        int rel = fid / FILL_CHUNKS;
        int chunk = fid - rel * FILL_CHUNKS;
        int e0 = (chunk * 256 + tid) * 4;
        if (e0 >= N_EDGES) return;
        const int* src = edges + (size_t)(rel * 2 + 0) * N_EDGES;
        const int* dst = edges + (size_t)(rel * 2 + 1) * N_EDGES;
        int4 s4 = *(const int4*)(src + e0);
        int4 t4 = *(const int4*)(dst + e0);
        int ss[4] = {s4.x, s4.y, s4.z, s4.w};
        int tt[4] = {t4.x, t4.y, t4.z, t4.w};
        #pragma unroll
        for (int k = 0; k < 4; ++k) {
            atomicAdd(deg_pad + ((size_t)(rel * N_NODES + ss[k]) << CPAD), 1);
            int p = atomicAdd(cur_pad + ((size_t)(rel * N_NODES + tt[k]) << CPAD), 1);
            if (p < ELL_W) {
                ell[(size_t)(rel * N_NODES + tt[k]) * ELL_W + p] = ss[k];
            } else {
                int i = atomicAdd(ovf_cnt, 1);
                if (i < OVF_CAP) ovf[i] = make_int2(ss[k], tt[k] | (rel << 20));
            }
        }
    }
}

// out[n,:] = (1/3) sum_r rsqrt(deg_in_r[n]) * sum_e rsqrt(deg_out_r[src_e]) *
//            h[src_e, r*128:(r+1)*128] + bsum
__global__ __launch_bounds__(256) void gather_kernel(
    const ushort* __restrict__ h, const int* __restrict__ deg_pad,
    const int* __restrict__ cur_pad, const int* __restrict__ ell,
    const float* __restrict__ bsum, float* __restrict__ out) {
    int w = threadIdx.x >> 6, l = threadIdx.x & 63;
    int n = blockIdx.x * 4 + w;
    if (n >= N_NODES) return;
    float ox = 0.f, oy = 0.f;
    #pragma unroll
    for (int r = 0; r < 3; ++r) {
        int base = r * N_NODES + n;
        int deg = cur_pad[(size_t)base << CPAD];
        int cnt = min(deg, ELL_W);
        int e = 0;
        float sc = 0.f;
        if (l < cnt) {
            e = ell[(size_t)base * ELL_W + l];
            sc = rsqrtf((float)max(deg_pad[(size_t)(r * N_NODES + e) << CPAD], 1));
        }
        float ax = 0.f, ay = 0.f;
        int i = 0;
        for (; i + 2 <= cnt; i += 2) {
            int s0 = __shfl(e, i), s1 = __shfl(e, i + 1);
            float c0 = __shfl(sc, i), c1 = __shfl(sc, i + 1);
            uint u0 = *(const uint*)(h + (size_t)s0 * 384 + r * 128 + 2 * l);
            uint u1 = *(const uint*)(h + (size_t)s1 * 384 + r * 128 + 2 * l);
            __half2 h0 = __builtin_bit_cast(__half2, u0);
            __half2 h1 = __builtin_bit_cast(__half2, u1);
            ax = fmaf(__low2float(h0), c0, ax);
            ay = fmaf(__high2float(h0), c0, ay);
            ax = fmaf(__low2float(h1), c1, ax);
            ay = fmaf(__high2float(h1), c1, ay);
        }
        if (i < cnt) {
            int s0 = __shfl(e, i);
            float c0 = __shfl(sc, i);
            uint u0 = *(const uint*)(h + (size_t)s0 * 384 + r * 128 + 2 * l);
            __half2 h0 = __builtin_bit_cast(__half2, u0);
            ax = fmaf(__low2float(h0), c0, ax);
            ay = fmaf(__high2float(h0), c0, ay);
        }
        float rdi = rsqrtf((float)max(deg, 1));
        ox = fmaf(ax, rdi, ox);
        oy = fmaf(ay, rdi, oy);
    }
    float2 bs = *(const float2*)(bsum + 2 * l);
    float2 o;
    o.x = ox * (1.f / 3.f) + bs.x;
    o.y = oy * (1.f / 3.f) + bs.y;
    *(float2*)(out + (size_t)n * 128 + 2 * l) = o;
}

// Rare path: in-degree > ELL_W. Atomic add into out (runs after gather).
__global__ void ovf_kernel(const ushort* __restrict__ h, const int* __restrict__ deg_pad,
                           const int* __restrict__ cur_pad,
                           const int* __restrict__ ovf_cnt, const int2* __restrict__ ovf,
                           float* out) {
    int m = min(*ovf_cnt, OVF_CAP);
    int total = m * 64;
    for (int idx = blockIdx.x * blockDim.x + threadIdx.x; idx < total;
         idx += blockDim.x * gridDim.x) {
        int ent = idx >> 6, l = idx & 63;
        int s = ovf[ent].x;
        int packed = ovf[ent].y;
        int t = packed & 0xFFFFF, r = packed >> 20;
        uint u = *(const uint*)(h + (size_t)s * 384 + r * 128 + 2 * l);
        __half2 hv = __builtin_bit_cast(__half2, u);
        float rdo = rsqrtf((float)max(deg_pad[(size_t)(r * N_NODES + s) << CPAD], 1));
        float rdi = rsqrtf((float)max(cur_pad[(size_t)(r * N_NODES + t) << CPAD], 1));
        float sc = rdo * rdi * (1.f / 3.f);
        atomicAdd(out + (size_t)t * 128 + 2 * l + 0, __low2float(hv) * sc);
        atomicAdd(out + (size_t)t * 128 + 2 * l + 1, __high2float(hv) * sc);
    }
}

extern "C" void kernel_launch(void* const* d_in, const int* in_sizes, int n_in,
                              void* d_out, int out_size, void* d_ws, size_t ws_size,
                              hipStream_t stream) {
    const float* x     = (const float*)d_in[0];
    const int*   edges = (const int*)d_in[1];   // [R][2][E] int32
    const float* W     = (const float*)d_in[2]; // [R][D][D]
    const float* b     = (const float*)d_in[3]; // [R][D]
    float* out = (float*)d_out;

    char* ws = (char*)d_ws;
    size_t off = 0;
    auto alloc = [&](size_t bytes) -> void* {
        void* p = ws + off;
        off += (bytes + 255) & ~(size_t)255;
        return p;
    };
    int*   deg_pad = (int*)alloc(((size_t)NTOT << CPAD) * 4);   // 9.6 MB
    int*   cur_pad = (int*)alloc(((size_t)NTOT << CPAD) * 4);   // 9.6 MB
    int*   ovf_cnt = (int*)alloc(256);
    size_t zero_bytes = off;                    // memset deg_pad+cur_pad+ovf_cnt
    float* bsum    = (float*)alloc((size_t)D * 4);
    ushort* Wt     = (ushort*)alloc((size_t)3 * D * D * 2);
    int2*  ovf     = (int2*)alloc((size_t)OVF_CAP * 8);
    int*   ell     = (int*)alloc((size_t)NTOT * ELL_W * 4);        // 14.4 MB
    ushort* h      = (ushort*)alloc((size_t)N_NODES * 3 * D * 2);  // 76.8 MB

    hipMemsetAsync(ws, 0, zero_bytes, stream);
    prep_w_kernel<<<192, 256, 0, stream>>>(W, b, Wt, bsum);
    fused_kernel<<<GEMM_BLKS + FILL_BLKS, 256, 0, stream>>>(
        x, Wt, edges, h, deg_pad, cur_pad, ell, ovf_cnt, ovf);
    gather_kernel<<<(N_NODES + 3) / 4, 256, 0, stream>>>(
        h, deg_pad, cur_pad, ell, bsum, out);
    ovf_kernel<<<16, 256, 0, stream>>>(h, deg_pad, cur_pad, ovf_cnt, ovf, out);
}

// Round 7
// 174.518 us; speedup vs baseline: 3.8128x; 1.2065x over previous
//
#include <hip/hip_runtime.h>
#include <hip/hip_fp16.h>
#include <math.h>

#define N_NODES 100000
#define N_RELS  3
#define N_EDGES 400000
#define D       128
#define NTOT    (N_RELS * N_NODES)   // 300000
#define ELL_W   12
#define OVF_CAP 4096
#define BSH     9                    // bucket = node >> 9 (512 nodes/bucket)
#define NB      196                  // ceil(100000/512)
#define BCAP    3072                 // per (rel,bucket) segment capacity (mean 2041, +23 sigma)
#define CHUNK   4096                 // edges per pass1 block
#define NCH     98                   // ceil(400000/4096)
#define PASS1_BLKS (NCH * N_RELS)    // 294
#define GEMM_BLKS  782               // ceil(100000/128)

typedef _Float16 f16x8 __attribute__((ext_vector_type(8)));
typedef float    f32x4 __attribute__((ext_vector_type(4)));

// W transpose + fp16 convert: Wt[r][j][k] = fp16(W[r][k][j]); bsum[j] = mean_r b[r][j]
__global__ void prep_w_kernel(const float* __restrict__ W, const float* __restrict__ b,
                              ushort* __restrict__ Wt, float* __restrict__ bsum) {
    int id = blockIdx.x * 256 + threadIdx.x;
    if (id < 3 * D * D) {
        int r = id >> 14;
        int rem = id & 16383;
        int k = rem >> 7, j = rem & 127;
        Wt[r * 16384 + j * 128 + k] = __builtin_bit_cast(ushort, (_Float16)W[id]);
    }
    if (blockIdx.x == 0 && threadIdx.x < D) {
        int j = threadIdx.x;
        bsum[j] = (b[j] + b[D + j] + b[2 * D + j]) * (1.0f / 3.0f);
    }
}

// Fused: GEMM blocks compute h = fp16(x @ W_rel); pass1 blocks bucket-partition
// edges (dst-partition as (s,t) pairs, src-partition as s) with one global
// atomic per (block,bucket) segment reservation.
__global__ __launch_bounds__(256) void fused_kernel(
    const float* __restrict__ x, const ushort* __restrict__ Wt,
    const int* __restrict__ edges, ushort* __restrict__ h,
    int2* __restrict__ part_dst, int* __restrict__ part_src,
    int* __restrict__ gcur_dst, int* __restrict__ gcur_src) {
    __shared__ union {
        ushort Bt[128 * 128];                       // 32 KB (gemm role)
        struct { int s[CHUNK]; int t[CHUNK]; } st;  // 32 KB (pass1 role)
    } U;
    __shared__ int histd[NB], hists[NB], segd[NB], segs[NB];

    const int bid = blockIdx.x;
    const int tid = threadIdx.x;
    bool is_fill;
    int gid;
    if (bid < 2 * PASS1_BLKS) { is_fill = (bid & 1); gid = bid >> 1; }
    else                      { is_fill = false;     gid = bid - PASS1_BLKS; }

    if (!is_fill) {
        const int n0 = gid * 128;
        const int w = tid >> 6, l = tid & 63;
        const int wrow = w * 32;
        const int lr = l & 15, lk = (l >> 4) * 8;

        f16x8 a[2][4];
        #pragma unroll
        for (int fi = 0; fi < 2; ++fi) {
            int row = n0 + wrow + fi * 16 + lr;
            row = min(row, N_NODES - 1);
            const float* xp = x + (size_t)row * 128 + lk;
            #pragma unroll
            for (int ks = 0; ks < 4; ++ks) {
                float4 va = *(const float4*)(xp + ks * 32);
                float4 vb = *(const float4*)(xp + ks * 32 + 4);
                f16x8 t;
                t[0] = (_Float16)va.x; t[1] = (_Float16)va.y;
                t[2] = (_Float16)va.z; t[3] = (_Float16)va.w;
                t[4] = (_Float16)vb.x; t[5] = (_Float16)vb.y;
                t[6] = (_Float16)vb.z; t[7] = (_Float16)vb.w;
                a[fi][ks] = t;
            }
        }

        for (int rel = 0; rel < 3; ++rel) {
            __syncthreads();
            {
                const ushort* Wg = Wt + rel * 16384;
                #pragma unroll
                for (int c = 0; c < 8; ++c) {
                    int id = c * 256 + tid;
                    int j = id >> 4, k8 = id & 15;
                    uint4 v = *(const uint4*)(Wg + j * 128 + k8 * 8);
                    int ba = (j * 256 + k8 * 16) ^ ((j & 7) << 4);
                    *(uint4*)((char*)U.Bt + ba) = v;
                }
            }
            __syncthreads();

            f32x4 acc[2][8];
            #pragma unroll
            for (int fi = 0; fi < 2; ++fi)
                #pragma unroll
                for (int fj = 0; fj < 8; ++fj)
                    acc[fi][fj] = (f32x4){0.f, 0.f, 0.f, 0.f};

            #pragma unroll
            for (int ks = 0; ks < 4; ++ks) {
                f16x8 bfr[8];
                #pragma unroll
                for (int fj = 0; fj < 8; ++fj) {
                    int j = fj * 16 + lr;
                    int ba = (j * 256 + (ks * 32 + lk) * 2) ^ ((j & 7) << 4);
                    bfr[fj] = *(f16x8*)((char*)U.Bt + ba);
                }
                #pragma unroll
                for (int fi = 0; fi < 2; ++fi)
                    #pragma unroll
                    for (int fj = 0; fj < 8; ++fj)
                        acc[fi][fj] = __builtin_amdgcn_mfma_f32_16x16x32_f16(
                            a[fi][ks], bfr[fj], acc[fi][fj], 0, 0, 0);
            }

            const int cr4 = (l >> 4) * 4;
            #pragma unroll
            for (int fi = 0; fi < 2; ++fi) {
                int rbase = n0 + wrow + fi * 16 + cr4;
                #pragma unroll
                for (int fj = 0; fj < 8; ++fj) {
                    int col = fj * 16 + lr;
                    #pragma unroll
                    for (int i = 0; i < 4; ++i) {
                        int row = rbase + i;
                        if (row < N_NODES)
                            h[(size_t)row * 384 + rel * 128 + col] =
                                __builtin_bit_cast(ushort, (_Float16)acc[fi][fj][i]);
                    }
                }
            }
        }
    } else {
        const int rel   = gid / NCH;
        const int chunk = gid - rel * NCH;
        const int e0 = chunk * CHUNK;
        const int ne = min(CHUNK, N_EDGES - e0);
        const int* src = edges + (size_t)(rel * 2 + 0) * N_EDGES;
        const int* dst = edges + (size_t)(rel * 2 + 1) * N_EDGES;

        for (int i = tid; i < NB; i += 256) { histd[i] = 0; hists[i] = 0; }
        __syncthreads();
        for (int i = tid; i < ne; i += 256) {
            int s = src[e0 + i], t = dst[e0 + i];
            U.st.s[i] = s; U.st.t[i] = t;
            atomicAdd(&histd[t >> BSH], 1);
            atomicAdd(&hists[s >> BSH], 1);
        }
        __syncthreads();
        for (int i = tid; i < NB; i += 256) {
            int hd = histd[i];
            segd[i] = hd ? atomicAdd(&gcur_dst[rel * NB + i], hd) : 0;
            int hs = hists[i];
            segs[i] = hs ? atomicAdd(&gcur_src[rel * NB + i], hs) : 0;
            histd[i] = 0; hists[i] = 0;   // reuse as local cursors
        }
        __syncthreads();
        for (int i = tid; i < ne; i += 256) {
            int s = U.st.s[i], t = U.st.t[i];
            int bd = t >> BSH;
            int p = segd[bd] + atomicAdd(&histd[bd], 1);
            if (p < BCAP) part_dst[(size_t)(rel * NB + bd) * BCAP + p] = make_int2(s, t);
            int bs = s >> BSH;
            int q = segs[bs] + atomicAdd(&hists[bs], 1);
            if (q < BCAP) part_src[(size_t)(rel * NB + bs) * BCAP + q] = s;
        }
    }
}

// Per (bucket, rel): build 12-wide ELL + degrees in LDS, write dense.
__global__ __launch_bounds__(256) void pass2_kernel(
    const int2* __restrict__ part_dst, const int* __restrict__ part_src,
    const int* __restrict__ gcur_dst, const int* __restrict__ gcur_src,
    int* __restrict__ ell, int* __restrict__ deg_in, int* __restrict__ deg_out,
    int* __restrict__ ovf_cnt, int2* __restrict__ ovf) {
    __shared__ int cnt[512];
    __shared__ int lell[512 * ELL_W];   // 24 KB
    const int b = blockIdx.x, rel = blockIdx.y;
    const int tid = threadIdx.x;
    const int n0 = b << BSH;
    const int nvalid = min(512, N_NODES - n0);

    for (int i = tid; i < 512; i += 256) cnt[i] = 0;
    __syncthreads();
    const int m = min(gcur_dst[rel * NB + b], BCAP);
    const int2* pp = part_dst + (size_t)(rel * NB + b) * BCAP;
    for (int i = tid; i < m; i += 256) {
        int2 e = pp[i];
        int li = e.y - n0;
        int p = atomicAdd(&cnt[li], 1);
        if (p < ELL_W) lell[li * ELL_W + p] = e.x;
        else {
            int o = atomicAdd(ovf_cnt, 1);
            if (o < OVF_CAP) ovf[o] = make_int2(e.x, e.y | (rel << 20));
        }
    }
    __syncthreads();
    for (int i = tid; i < nvalid; i += 256)
        deg_in[rel * N_NODES + n0 + i] = cnt[i];
    // ELL layout [rel][node][ELL_W] -> contiguous block per bucket
    for (int i = tid; i < nvalid * ELL_W; i += 256)
        ell[(size_t)(rel * N_NODES + n0) * ELL_W + i] = lell[i];
    __syncthreads();
    for (int i = tid; i < 512; i += 256) cnt[i] = 0;
    __syncthreads();
    const int m2 = min(gcur_src[rel * NB + b], BCAP);
    const int* ps = part_src + (size_t)(rel * NB + b) * BCAP;
    for (int i = tid; i < m2; i += 256) atomicAdd(&cnt[ps[i] - n0], 1);
    __syncthreads();
    for (int i = tid; i < nvalid; i += 256)
        deg_out[rel * N_NODES + n0 + i] = cnt[i];
}

// out[n,:] = (1/3) sum_r rsqrt(deg_in_r[n]) * sum_e rsqrt(deg_out_r[src_e]) *
//            h[src_e, r*128:(r+1)*128] + bsum
__global__ __launch_bounds__(256) void gather_kernel(
    const ushort* __restrict__ h, const int* __restrict__ deg_in,
    const int* __restrict__ deg_out, const int* __restrict__ ell,
    const float* __restrict__ bsum, float* __restrict__ out) {
    int w = threadIdx.x >> 6, l = threadIdx.x & 63;
    int n = blockIdx.x * 4 + w;
    if (n >= N_NODES) return;
    float ox = 0.f, oy = 0.f;
    #pragma unroll
    for (int r = 0; r < 3; ++r) {
        int base = r * N_NODES + n;
        int deg = deg_in[base];
        int cnt = min(deg, ELL_W);
        int e = 0;
        float sc = 0.f;
        if (l < cnt) {
            e = ell[(size_t)base * ELL_W + l];
            sc = rsqrtf((float)max(deg_out[r * N_NODES + e], 1));
        }
        float ax = 0.f, ay = 0.f;
        int i = 0;
        for (; i + 2 <= cnt; i += 2) {
            int s0 = __shfl(e, i), s1 = __shfl(e, i + 1);
            float c0 = __shfl(sc, i), c1 = __shfl(sc, i + 1);
            uint u0 = *(const uint*)(h + (size_t)s0 * 384 + r * 128 + 2 * l);
            uint u1 = *(const uint*)(h + (size_t)s1 * 384 + r * 128 + 2 * l);
            __half2 h0 = __builtin_bit_cast(__half2, u0);
            __half2 h1 = __builtin_bit_cast(__half2, u1);
            ax = fmaf(__low2float(h0), c0, ax);
            ay = fmaf(__high2float(h0), c0, ay);
            ax = fmaf(__low2float(h1), c1, ax);
            ay = fmaf(__high2float(h1), c1, ay);
        }
        if (i < cnt) {
            int s0 = __shfl(e, i);
            float c0 = __shfl(sc, i);
            uint u0 = *(const uint*)(h + (size_t)s0 * 384 + r * 128 + 2 * l);
            __half2 h0 = __builtin_bit_cast(__half2, u0);
            ax = fmaf(__low2float(h0), c0, ax);
            ay = fmaf(__high2float(h0), c0, ay);
        }
        float rdi = rsqrtf((float)max(deg, 1));
        ox = fmaf(ax, rdi, ox);
        oy = fmaf(ay, rdi, oy);
    }
    float2 bs = *(const float2*)(bsum + 2 * l);
    float2 o;
    o.x = ox * (1.f / 3.f) + bs.x;
    o.y = oy * (1.f / 3.f) + bs.y;
    *(float2*)(out + (size_t)n * 128 + 2 * l) = o;
}

// Rare path: in-degree > ELL_W. Atomic add into out (runs after gather).
__global__ void ovf_kernel(const ushort* __restrict__ h, const int* __restrict__ deg_in,
                           const int* __restrict__ deg_out,
                           const int* __restrict__ ovf_cnt, const int2* __restrict__ ovf,
                           float* out) {
    int m = min(*ovf_cnt, OVF_CAP);
    int total = m * 64;
    for (int idx = blockIdx.x * blockDim.x + threadIdx.x; idx < total;
         idx += blockDim.x * gridDim.x) {
        int ent = idx >> 6, l = idx & 63;
        int s = ovf[ent].x;
        int packed = ovf[ent].y;
        int t = packed & 0xFFFFF, r = packed >> 20;
        uint u = *(const uint*)(h + (size_t)s * 384 + r * 128 + 2 * l);
        __half2 hv = __builtin_bit_cast(__half2, u);
        float rdo = rsqrtf((float)max(deg_out[r * N_NODES + s], 1));
        float rdi = rsqrtf((float)max(deg_in[r * N_NODES + t], 1));
        float sc = rdo * rdi * (1.f / 3.f);
        atomicAdd(out + (size_t)t * 128 + 2 * l + 0, __low2float(hv) * sc);
        atomicAdd(out + (size_t)t * 128 + 2 * l + 1, __high2float(hv) * sc);
    }
}

extern "C" void kernel_launch(void* const* d_in, const int* in_sizes, int n_in,
                              void* d_out, int out_size, void* d_ws, size_t ws_size,
                              hipStream_t stream) {
    const float* x     = (const float*)d_in[0];
    const int*   edges = (const int*)d_in[1];   // [R][2][E] int32
    const float* W     = (const float*)d_in[2]; // [R][D][D]
    const float* b     = (const float*)d_in[3]; // [R][D]
    float* out = (float*)d_out;

    char* ws = (char*)d_ws;
    size_t off = 0;
    auto alloc = [&](size_t bytes) -> void* {
        void* p = ws + off;
        off += (bytes + 255) & ~(size_t)255;
        return p;
    };
    int*   gcur_dst = (int*)alloc((size_t)N_RELS * NB * 4);
    int*   gcur_src = (int*)alloc((size_t)N_RELS * NB * 4);
    int*   ovf_cnt  = (int*)alloc(256);
    size_t zero_bytes = off;                    // memset the three above
    float* bsum     = (float*)alloc((size_t)D * 4);
    ushort* Wt      = (ushort*)alloc((size_t)3 * D * D * 2);
    int2*  ovf      = (int2*)alloc((size_t)OVF_CAP * 8);
    int2*  part_dst = (int2*)alloc((size_t)N_RELS * NB * BCAP * 8);   // 13.8 MB
    int*   part_src = (int*)alloc((size_t)N_RELS * NB * BCAP * 4);    //  6.9 MB
    int*   ell      = (int*)alloc((size_t)NTOT * ELL_W * 4);          // 14.4 MB
    int*   deg_in   = (int*)alloc((size_t)NTOT * 4);
    int*   deg_out  = (int*)alloc((size_t)NTOT * 4);
    ushort* h       = (ushort*)alloc((size_t)N_NODES * 3 * D * 2);    // 76.8 MB

    hipMemsetAsync(ws, 0, zero_bytes, stream);
    prep_w_kernel<<<192, 256, 0, stream>>>(W, b, Wt, bsum);
    fused_kernel<<<GEMM_BLKS + PASS1_BLKS, 256, 0, stream>>>(
        x, Wt, edges, h, part_dst, part_src, gcur_dst, gcur_src);
    pass2_kernel<<<dim3(NB, 3), 256, 0, stream>>>(
        part_dst, part_src, gcur_dst, gcur_src, ell, deg_in, deg_out, ovf_cnt, ovf);
    gather_kernel<<<(N_NODES + 3) / 4, 256, 0, stream>>>(
        h, deg_in, deg_out, ell, bsum, out);
    ovf_kernel<<<16, 256, 0, stream>>>(h, deg_in, deg_out, ovf_cnt, ovf, out);
}